// Round 2
// baseline (898.582 us; speedup 1.0000x reference)
//
#include <hip/hip_runtime.h>
#include <math.h>
#include <string.h>

#define SX 84  // LDS stride for x halo tile (80 wide), odd multiple of 4 floats
#define SH 68  // LDS stride for h-pass output (64 wide), odd multiple of 4 floats

// Composed 1-D operator weights: interior 13-tap + 6 boundary rows (top; bottom mirrors)
struct GW { float c[13]; float b[6][13]; };

__global__ __launch_bounds__(256) void zero_k(float* __restrict__ out, float* __restrict__ S) {
  int i = blockIdx.x * 256 + threadIdx.x;
  if (i < 65536) out[i] = 0.f;
  if (i < 1024) S[i] = 0.f;
}

__device__ __forceinline__ float4 ldsf4(const float* p) { return *(const float4*)p; }

__device__ __forceinline__ float wat(const GW& W, int pos, int t) {
  if (pos < 6) return W.b[pos][t];
  if (pos > 249) return W.b[255 - pos][12 - t];
  return W.c[t];
}

// One block = one 64x64 tile of one (b,c) image. ctx = x - Vc(Hc(x)), exact incl. borders.
__global__ __launch_bounds__(256) void blur_k(const float* __restrict__ x,
                                              float* __restrict__ ctx,
                                              float* __restrict__ S,
                                              GW W) {
  __shared__ __align__(16) float xb[76 * SX];  // halo tile: rows [oy-6,oy+70) x cols [ox-8,ox+72)
  __shared__ __align__(16) float hb[76 * SH];  // h-pass: 76 rows x 64 cols

  const int tid = threadIdx.x;
  const int bi = blockIdx.x;
  const int img = bi >> 4;            // 1024 images
  const int tile = bi & 15;           // 4x4 tiles of 64x64
  const int oy = (tile >> 2) << 6;
  const int ox = (tile & 3) << 6;
  const float* xg = x + ((size_t)img << 16);

  // ---- load halo: 76 rows x 20 float4 units (cols ox-8 .. ox+72, 16B-aligned)
  for (int u = tid; u < 76 * 20; u += 256) {
    int r = u / 20, cu = u % 20;
    int gy = oy + r - 6;
    int gx = ox + (cu << 2) - 8;
    float4 v = make_float4(0.f, 0.f, 0.f, 0.f);
    if ((unsigned)gy < 256u) {
      const float* rp = xg + gy * 256 + gx;
      if (gx >= 0 && gx + 3 < 256) {
        v = *(const float4*)rp;
      } else {
        if ((unsigned)(gx + 0) < 256u) v.x = rp[0];
        if ((unsigned)(gx + 1) < 256u) v.y = rp[1];
        if ((unsigned)(gx + 2) < 256u) v.z = rp[2];
        if ((unsigned)(gx + 3) < 256u) v.w = rp[3];
      }
    }
    *(float4*)&xb[r * SX + (cu << 2)] = v;
  }
  __syncthreads();

  // ---- h-pass: hb[r][c] = sum_t w(gx)[t] * x[r][gx-6+t], 76 rows x 16 units
  for (int u = tid; u < 76 * 16; u += 256) {
    int r = u >> 4, cu = u & 15;
    const float* p = &xb[r * SX + (cu << 2)];
    float v[20];
    *(float4*)&v[0]  = ldsf4(p);
    *(float4*)&v[4]  = ldsf4(p + 4);
    *(float4*)&v[8]  = ldsf4(p + 8);
    *(float4*)&v[12] = ldsf4(p + 12);
    *(float4*)&v[16] = ldsf4(p + 16);
    int gx0 = ox + (cu << 2);
    float o[4] = {0.f, 0.f, 0.f, 0.f};
    if (gx0 >= 6 && gx0 + 3 <= 249) {
      #pragma unroll
      for (int t = 0; t < 13; ++t) {
        float w = W.c[t];
        o[0] += w * v[2 + t];
        o[1] += w * v[3 + t];
        o[2] += w * v[4 + t];
        o[3] += w * v[5 + t];
      }
    } else {
      #pragma unroll
      for (int j = 0; j < 4; ++j) {
        int g = gx0 + j;
        float acc = 0.f;
        #pragma unroll
        for (int t = 0; t < 13; ++t) acc += wat(W, g, t) * v[2 + j + t];
        o[j] = acc;
      }
    }
    *(float4*)&hb[r * SH + (cu << 2)] = make_float4(o[0], o[1], o[2], o[3]);
  }
  __syncthreads();

  // ---- v-pass (streamed): thread (rg,cu) computes rows 4rg..4rg+3 at col unit cu,
  //      then ctx = x - G3 and exp partial sum. hb row k feeds output r with tap t=k-r.
  const int rg = tid >> 4, cu = tid & 15;
  const int gy0 = oy + (rg << 2);
  float4 acc[4];
  acc[0] = acc[1] = acc[2] = acc[3] = make_float4(0.f, 0.f, 0.f, 0.f);
  if (gy0 >= 6 && gy0 + 3 <= 249) {
    #pragma unroll
    for (int k = 0; k < 16; ++k) {
      float4 s = ldsf4(&hb[((rg << 2) + k) * SH + (cu << 2)]);
      #pragma unroll
      for (int r = 0; r < 4; ++r) {
        int t = k - r;
        if (t >= 0 && t <= 12) {
          float w = W.c[t];
          acc[r].x += w * s.x; acc[r].y += w * s.y; acc[r].z += w * s.z; acc[r].w += w * s.w;
        }
      }
    }
  } else {
    #pragma unroll
    for (int k = 0; k < 16; ++k) {
      float4 s = ldsf4(&hb[((rg << 2) + k) * SH + (cu << 2)]);
      #pragma unroll
      for (int r = 0; r < 4; ++r) {
        int t = k - r;
        if (t >= 0 && t <= 12) {
          float w = wat(W, gy0 + r, t);
          acc[r].x += w * s.x; acc[r].y += w * s.y; acc[r].z += w * s.z; acc[r].w += w * s.w;
        }
      }
    }
  }

  float le = 0.f;
  #pragma unroll
  for (int r = 0; r < 4; ++r) {
    int rr = (rg << 2) + r;
    float4 xv = ldsf4(&xb[(rr + 6) * SX + (cu << 2) + 8]);
    float4 cv = make_float4(xv.x - acc[r].x, xv.y - acc[r].y, xv.z - acc[r].z, xv.w - acc[r].w);
    size_t base = ((size_t)img << 16) + (size_t)(oy + rr) * 256 + (ox + (cu << 2));
    *(float4*)&ctx[base] = cv;
    le += __expf(cv.x) + __expf(cv.y) + __expf(cv.z) + __expf(cv.w);
  }
  #pragma unroll
  for (int off = 32; off >= 1; off >>= 1) le += __shfl_down(le, off);
  if ((tid & 63) == 0) atomicAdd(&S[img], le);
}

// att accumulation: block = (chunk ci of 1024 n's, batch b).
__global__ __launch_bounds__(256) void att_k(const float* __restrict__ ctx,
                                             float* __restrict__ attacc) {
  __shared__ __align__(16) float ct[64 * 68];
  __shared__ __align__(16) float et[64 * 68];
  const int t = threadIdx.x;
  const int ci = blockIdx.x;
  const int b = blockIdx.y;
  const int d0 = (t >> 4) << 2;
  const int e0 = (t & 15) << 2;
  const float* cb = ctx + ((size_t)b << 22);
  float acc[4][4] = {};
  for (int sub = 0; sub < 16; ++sub) {
    const int n0 = (ci << 10) + (sub << 6);
    #pragma unroll
    for (int i = 0; i < 16; ++i) {
      int e = i * 256 + t;
      int d = e >> 6, nl = e & 63;
      float v = cb[((size_t)d << 16) + n0 + nl];
      ct[nl * 68 + d] = v;
      et[nl * 68 + d] = __expf(v);
    }
    __syncthreads();
    #pragma unroll 16
    for (int nl = 0; nl < 64; ++nl) {
      float4 ed = *(const float4*)&et[nl * 68 + d0];
      float4 cv = *(const float4*)&ct[nl * 68 + e0];
      acc[0][0] += ed.x * cv.x; acc[0][1] += ed.x * cv.y; acc[0][2] += ed.x * cv.z; acc[0][3] += ed.x * cv.w;
      acc[1][0] += ed.y * cv.x; acc[1][1] += ed.y * cv.y; acc[1][2] += ed.y * cv.z; acc[1][3] += ed.y * cv.w;
      acc[2][0] += ed.z * cv.x; acc[2][1] += ed.z * cv.y; acc[2][2] += ed.z * cv.z; acc[2][3] += ed.z * cv.w;
      acc[3][0] += ed.w * cv.x; acc[3][1] += ed.w * cv.y; acc[3][2] += ed.w * cv.z; acc[3][3] += ed.w * cv.w;
    }
    __syncthreads();
  }
  float* ap = attacc + ((size_t)(b * 64 + d0) << 6) + e0;
  #pragma unroll
  for (int i = 0; i < 4; ++i) {
    #pragma unroll
    for (int j = 0; j < 4; ++j) atomicAdd(ap + ((size_t)i << 6) + j, acc[i][j]);
  }
}

__global__ __launch_bounds__(256) void fin_k(float* __restrict__ out, const float* __restrict__ S) {
  int i = blockIdx.x * 256 + threadIdx.x;
  out[i] = out[i] / S[i >> 6];
}

extern "C" void kernel_launch(void* const* d_in, const int* in_sizes, int n_in,
                              void* d_out, int out_size, void* d_ws, size_t ws_size,
                              hipStream_t stream) {
  const float* x = (const float*)d_in[0];
  float* out = (float*)d_out;
  float* ctx = (float*)d_ws;                                   // 256 MiB fp32
  float* S = (float*)((char*)d_ws + (size_t)67108864 * 4);
  if (ws_size < (size_t)67108864 * 4 + 4096) return;

  // ---- host: per-level 1-D gaussians (double, matches cv2/getGaussianKernel)
  double gg[3][7];
  double sv = pow(2.0, 1.0 / 3.0);
  for (int lv = 0; lv < 3; ++lv) {
    int k = 2 * lv + 3;
    double sig = 1.6 * pow(sv, lv), sum = 0.0;
    for (int i = 0; i < k; ++i) {
      double a = i - (k - 1) / 2.0;
      gg[lv][i] = exp(-a * a / (2.0 * sig * sig));
      sum += gg[lv][i];
    }
    for (int i = 0; i < k; ++i) gg[lv][i] /= sum;
  }

  // ---- composed 1-D operator Hc = A7*A5*A3 (truncated-Toeplitz product).
  // Row i of Hc = (A3 A5 A7 e_i)^T (symmetric factors). Rows 0..5 boundary, row 6 interior.
  GW W;
  {
    const int L = 48;
    double e[L], a[L], b2[L], cc[L];
    auto conv1 = [&](double* o, const double* in, const double* g, int k) {
      int c = (k - 1) / 2;
      for (int j = 0; j < L; ++j) {
        double s = 0.0;
        for (int t = 0; t < k; ++t) {
          int idx = j - c + t;
          if (idx >= 0 && idx < L) s += g[t] * in[idx];
        }
        o[j] = s;
      }
    };
    for (int i = 0; i <= 6; ++i) {
      memset(e, 0, sizeof(e)); e[i] = 1.0;
      conv1(a, e, gg[2], 7);
      conv1(b2, a, gg[1], 5);
      conv1(cc, b2, gg[0], 3);
      if (i < 6) {
        for (int t = 0; t < 13; ++t) {
          int j = i - 6 + t;
          W.b[i][t] = (j >= 0) ? (float)cc[j] : 0.f;
        }
      } else {
        for (int t = 0; t < 13; ++t) W.c[t] = (float)cc[t];
      }
    }
  }

  zero_k<<<dim3(256), dim3(256), 0, stream>>>(out, S);
  blur_k<<<dim3(16384), dim3(256), 0, stream>>>(x, ctx, S, W);
  att_k<<<dim3(64, 16), dim3(256), 0, stream>>>(ctx, out);
  fin_k<<<dim3(256), dim3(256), 0, stream>>>(out, S);
}

// Round 3
// 863.311 us; speedup vs baseline: 1.0409x; 1.0409x over previous
//
#include <hip/hip_runtime.h>
#include <math.h>

#define SXB 56  // xb stride (floats): 48 used; 56 mod 32 = 24 -> balanced b128 banks
#define SHB 44  // hb stride (floats): 32 used; 44 mod 32 = 12 -> balanced b128 banks

struct WC  { float c[13]; };                 // interior composed 13-tap
struct G157 { float g3[3], g5[5], g7[7]; };  // per-level 1-D gaussians

__device__ __forceinline__ float4 ldsf4(const float* p) { return *(const float4*)p; }

// zero out + S; block 0 builds the per-position composed weight table wtab[256][16]
// row g of (A7*A5*A3) with truncated (zero-pad) Toeplitz factors: exact SAME-conv compose.
__global__ __launch_bounds__(256) void zero_k(float* __restrict__ out, float* __restrict__ S,
                                              float* __restrict__ wtab, G157 gw) {
  int i = blockIdx.x * 256 + threadIdx.x;
  if (i < 65536) out[i] = 0.f;
  if (i < 1024) S[i] = 0.f;
  if (blockIdx.x == 0) {
    int g = threadIdx.x;  // position 0..255
    float row[13];
    #pragma unroll
    for (int t = 0; t < 13; ++t) row[t] = 0.f;
    #pragma unroll
    for (int di = -3; di <= 3; ++di) {
      int ii = g + di;
      if ((unsigned)ii >= 256u) continue;
      float w7 = gw.g7[di + 3];
      #pragma unroll
      for (int dj = -2; dj <= 2; ++dj) {
        int jj = ii + dj;
        if ((unsigned)jj >= 256u) continue;
        float c2 = w7 * gw.g5[dj + 2];
        #pragma unroll
        for (int dk = -1; dk <= 1; ++dk) {
          int mm = jj + dk;
          if ((unsigned)mm >= 256u) continue;
          row[di + dj + dk + 6] += c2 * gw.g3[dk + 1];  // t = di+dj+dk+6, compile-time
        }
      }
    }
    #pragma unroll
    for (int t = 0; t < 13; ++t) wtab[(g << 4) + t] = row[t];
    wtab[(g << 4) + 13] = 0.f; wtab[(g << 4) + 14] = 0.f; wtab[(g << 4) + 15] = 0.f;
  }
}

// One block = one 32x32 tile. ctx = x - Vc(Hc(x)) with exact boundary rows via wtab.
__global__ __launch_bounds__(256) void blur_k(const float* __restrict__ x,
                                              float* __restrict__ ctx,
                                              float* __restrict__ S,
                                              const float* __restrict__ wtab,
                                              WC wc) {
  __shared__ __align__(16) float xb[44 * SXB];  // rows oy-6..oy+37, cols ox-8..ox+39
  __shared__ __align__(16) float hb[44 * SHB];  // h-pass out: 44 rows x 32 cols

  const int tid = threadIdx.x;
  const int bi = blockIdx.x;
  const int img = bi >> 6;           // 1024 images
  const int tile = bi & 63;          // 8x8 tiles of 32x32
  const int oy = (tile >> 3) << 5;
  const int ox = (tile & 7) << 5;
  const float* xg = x + ((size_t)img << 16);
  const bool hfast = (ox >= 6) && (ox <= 218);
  const bool vfast = (oy >= 6) && (oy <= 218);

  // ---- load halo: 44 rows x 12 float4 units (16B-aligned global reads)
  for (int u = tid; u < 44 * 12; u += 256) {
    int r = u / 12, cu = u - r * 12;
    int gy = oy + r - 6;
    int gx = ox + (cu << 2) - 8;
    float4 v = make_float4(0.f, 0.f, 0.f, 0.f);
    if ((unsigned)gy < 256u) {
      const float* rp = xg + gy * 256 + gx;
      if (gx >= 0 && gx + 3 < 256) v = *(const float4*)rp;
      else {
        if ((unsigned)(gx + 0) < 256u) v.x = rp[0];
        if ((unsigned)(gx + 1) < 256u) v.y = rp[1];
        if ((unsigned)(gx + 2) < 256u) v.z = rp[2];
        if ((unsigned)(gx + 3) < 256u) v.w = rp[3];
      }
    }
    *(float4*)&xb[r * SXB + (cu << 2)] = v;
  }
  __syncthreads();

  // ---- h-pass: 44 rows x 8 units; out col gx0+j uses x cols gx0+j-6..+6
  for (int u = tid; u < 44 * 8; u += 256) {
    int r = u >> 3, cu = u & 7;
    const float* p = &xb[r * SXB + (cu << 2)];
    float v[20];
    *(float4*)&v[0]  = ldsf4(p);
    *(float4*)&v[4]  = ldsf4(p + 4);
    *(float4*)&v[8]  = ldsf4(p + 8);
    *(float4*)&v[12] = ldsf4(p + 12);
    *(float4*)&v[16] = ldsf4(p + 16);
    float o[4] = {0.f, 0.f, 0.f, 0.f};
    if (hfast) {
      #pragma unroll
      for (int t = 0; t < 13; ++t) {
        float w = wc.c[t];
        o[0] += w * v[2 + t]; o[1] += w * v[3 + t];
        o[2] += w * v[4 + t]; o[3] += w * v[5 + t];
      }
    } else {
      #pragma unroll
      for (int j = 0; j < 4; ++j) {
        const float* wr = wtab + ((ox + (cu << 2) + j) << 4);
        float a = 0.f;
        #pragma unroll
        for (int t = 0; t < 13; ++t) a += wr[t] * v[2 + j + t];
        o[j] = a;
      }
    }
    *(float4*)&hb[r * SHB + (cu << 2)] = make_float4(o[0], o[1], o[2], o[3]);
  }
  __syncthreads();

  // ---- v-pass: 256 units exactly (r=tid>>3, cu=tid&7); then ctx + exp partial
  const int r = tid >> 3, cu = tid & 7;
  float ax = 0.f, ay = 0.f, az = 0.f, aw = 0.f;
  if (vfast) {
    #pragma unroll
    for (int t = 0; t < 13; ++t) {
      float4 s = ldsf4(&hb[(r + t) * SHB + (cu << 2)]);
      float w = wc.c[t];
      ax += w * s.x; ay += w * s.y; az += w * s.z; aw += w * s.w;
    }
  } else {
    const float* wr = wtab + ((oy + r) << 4);
    #pragma unroll
    for (int t = 0; t < 13; ++t) {
      float4 s = ldsf4(&hb[(r + t) * SHB + (cu << 2)]);
      float w = wr[t];
      ax += w * s.x; ay += w * s.y; az += w * s.z; aw += w * s.w;
    }
  }
  float4 xv = ldsf4(&xb[(r + 6) * SXB + (cu << 2) + 8]);
  float4 cv = make_float4(xv.x - ax, xv.y - ay, xv.z - az, xv.w - aw);
  size_t base = ((size_t)img << 16) + (size_t)(oy + r) * 256 + (ox + (cu << 2));
  *(float4*)&ctx[base] = cv;
  float le = __expf(cv.x) + __expf(cv.y) + __expf(cv.z) + __expf(cv.w);
  #pragma unroll
  for (int off = 32; off >= 1; off >>= 1) le += __shfl_down(le, off);
  if ((tid & 63) == 0) atomicAdd(&S[img], le);
}

// att accumulation: block = (chunk ci of 1024 n's, batch b).
__global__ __launch_bounds__(256) void att_k(const float* __restrict__ ctx,
                                             float* __restrict__ attacc) {
  __shared__ __align__(16) float ct[64 * 68];
  __shared__ __align__(16) float et[64 * 68];
  const int t = threadIdx.x;
  const int ci = blockIdx.x;
  const int b = blockIdx.y;
  const int d0 = (t >> 4) << 2;
  const int e0 = (t & 15) << 2;
  const float* cb = ctx + ((size_t)b << 22);
  float acc[4][4] = {};
  for (int sub = 0; sub < 16; ++sub) {
    const int n0 = (ci << 10) + (sub << 6);
    #pragma unroll
    for (int i = 0; i < 16; ++i) {
      int e = i * 256 + t;
      int d = e >> 6, nl = e & 63;
      float v = cb[((size_t)d << 16) + n0 + nl];
      ct[nl * 68 + d] = v;
      et[nl * 68 + d] = __expf(v);
    }
    __syncthreads();
    #pragma unroll 16
    for (int nl = 0; nl < 64; ++nl) {
      float4 ed = *(const float4*)&et[nl * 68 + d0];
      float4 cv = *(const float4*)&ct[nl * 68 + e0];
      acc[0][0] += ed.x * cv.x; acc[0][1] += ed.x * cv.y; acc[0][2] += ed.x * cv.z; acc[0][3] += ed.x * cv.w;
      acc[1][0] += ed.y * cv.x; acc[1][1] += ed.y * cv.y; acc[1][2] += ed.y * cv.z; acc[1][3] += ed.y * cv.w;
      acc[2][0] += ed.z * cv.x; acc[2][1] += ed.z * cv.y; acc[2][2] += ed.z * cv.z; acc[2][3] += ed.z * cv.w;
      acc[3][0] += ed.w * cv.x; acc[3][1] += ed.w * cv.y; acc[3][2] += ed.w * cv.z; acc[3][3] += ed.w * cv.w;
    }
    __syncthreads();
  }
  float* ap = attacc + ((size_t)(b * 64 + d0) << 6) + e0;
  #pragma unroll
  for (int i = 0; i < 4; ++i) {
    #pragma unroll
    for (int j = 0; j < 4; ++j) atomicAdd(ap + ((size_t)i << 6) + j, acc[i][j]);
  }
}

__global__ __launch_bounds__(256) void fin_k(float* __restrict__ out, const float* __restrict__ S) {
  int i = blockIdx.x * 256 + threadIdx.x;
  out[i] = out[i] / S[i >> 6];
}

extern "C" void kernel_launch(void* const* d_in, const int* in_sizes, int n_in,
                              void* d_out, int out_size, void* d_ws, size_t ws_size,
                              hipStream_t stream) {
  const float* x = (const float*)d_in[0];
  float* out = (float*)d_out;
  float* ctx = (float*)d_ws;                                      // 256 MiB fp32
  float* S   = (float*)((char*)d_ws + (size_t)67108864 * 4);      // 4 KB
  float* wtab = (float*)((char*)d_ws + (size_t)67108864 * 4 + 4096);  // 16 KB
  if (ws_size < (size_t)67108864 * 4 + 4096 + 16384) return;

  // per-level 1-D gaussians in double (matches cv2.getGaussianKernel)
  double gg[3][7];
  double sv = pow(2.0, 1.0 / 3.0);
  for (int lv = 0; lv < 3; ++lv) {
    int k = 2 * lv + 3;
    double sig = 1.6 * pow(sv, lv), sum = 0.0;
    for (int i = 0; i < k; ++i) {
      double a = i - (k - 1) / 2.0;
      gg[lv][i] = exp(-a * a / (2.0 * sig * sig));
      sum += gg[lv][i];
    }
    for (int i = 0; i < k; ++i) gg[lv][i] /= sum;
  }

  G157 gw;
  for (int i = 0; i < 3; ++i) gw.g3[i] = (float)gg[0][i];
  for (int i = 0; i < 5; ++i) gw.g5[i] = (float)gg[1][i];
  for (int i = 0; i < 7; ++i) gw.g7[i] = (float)gg[2][i];

  // interior composed 13-tap (full convolution of the three kernels), in double
  WC wc;
  {
    double t35[7] = {0};           // g3 * g5 -> length 7
    for (int i = 0; i < 3; ++i)
      for (int j = 0; j < 5; ++j) t35[i + j] += gg[0][i] * gg[1][j];
    double t357[13] = {0};         // (g3*g5) * g7 -> length 13
    for (int i = 0; i < 7; ++i)
      for (int j = 0; j < 7; ++j) t357[i + j] += t35[i] * gg[2][j];
    for (int t = 0; t < 13; ++t) wc.c[t] = (float)t357[t];
  }

  zero_k<<<dim3(256), dim3(256), 0, stream>>>(out, S, wtab, gw);
  blur_k<<<dim3(65536), dim3(256), 0, stream>>>(x, ctx, S, wtab, wc);
  att_k<<<dim3(64, 16), dim3(256), 0, stream>>>(ctx, out);
  fin_k<<<dim3(256), dim3(256), 0, stream>>>(out, S);
}

// Round 4
// 333.125 us; speedup vs baseline: 2.6974x; 2.5916x over previous
//
#include <hip/hip_runtime.h>
#include <math.h>

struct WC   { float c[13]; };                 // interior composed 13-tap
struct G157 { float g3[3], g5[5], g7[7]; };   // per-level 1-D gaussians

// zero out + S; block 0 builds per-position composed weight table wtab[256][16]:
// row g of (A3*A5*A7 applied with per-stage zero-pad crops) — exact SAME-conv compose.
__global__ __launch_bounds__(256) void zero_k(float* __restrict__ out, float* __restrict__ S,
                                              float* __restrict__ wtab, G157 gw) {
  int i = blockIdx.x * 256 + threadIdx.x;
  if (i < 65536) out[i] = 0.f;
  if (i < 1024) S[i] = 0.f;
  if (blockIdx.x == 0) {
    int g = threadIdx.x;  // position 0..255
    float row[13];
    #pragma unroll
    for (int t = 0; t < 13; ++t) row[t] = 0.f;
    #pragma unroll
    for (int di = -3; di <= 3; ++di) {
      int ii = g + di;
      if ((unsigned)ii >= 256u) continue;
      float w7 = gw.g7[di + 3];
      #pragma unroll
      for (int dj = -2; dj <= 2; ++dj) {
        int jj = ii + dj;
        if ((unsigned)jj >= 256u) continue;
        float c2 = w7 * gw.g5[dj + 2];
        #pragma unroll
        for (int dk = -1; dk <= 1; ++dk) {
          int mm = jj + dk;
          if ((unsigned)mm >= 256u) continue;
          row[di + dj + dk + 6] += c2 * gw.g3[dk + 1];
        }
      }
    }
    #pragma unroll
    for (int t = 0; t < 13; ++t) wtab[(g << 4) + t] = row[t];
    wtab[(g << 4) + 13] = 0.f; wtab[(g << 4) + 14] = 0.f; wtab[(g << 4) + 15] = 0.f;
  }
}

// Register-rolling blur: block = 256 threads (one per column) sweeping a 64-row band.
// v-conv in registers (13-row rolling window), h-conv via one LDS row (double-buffered).
__global__ __launch_bounds__(256) void ctx_k(const float* __restrict__ x,
                                             float* __restrict__ ctx,
                                             float* __restrict__ S,
                                             const float* __restrict__ wtab,
                                             WC wc) {
  __shared__ float rb[2][268];   // v-result row, pad 6 each side (zeros)
  __shared__ float wl[96];       // boundary weight rows 0..5 (x16)

  const int tid = threadIdx.x;
  const int bi = blockIdx.x;
  const int img = bi >> 2;       // 1024 images
  const int band = bi & 3;       // 4 bands of 64 rows
  const int y0 = band << 6;
  const float* xg = x + ((size_t)img << 16);
  float* cg = ctx + ((size_t)img << 16);

  if (tid < 96) wl[tid] = wtab[tid];
  if (tid < 6) { rb[0][tid] = 0.f; rb[1][tid] = 0.f; }
  if (tid >= 250) { rb[0][tid + 12] = 0.f; rb[1][tid + 12] = 0.f; }

  // fill 13-row window: rows y0-6 .. y0+6 (zeros outside image)
  float win[13];
  #pragma unroll
  for (int i = 0; i < 13; ++i) {
    int yy = y0 - 6 + i;
    win[i] = ((unsigned)yy < 256u) ? xg[yy * 256 + tid] : 0.f;
  }
  __syncthreads();

  // h-direction boundary fixup parameters for this lane
  const bool hfix = (tid < 6) || (tid > 249);
  int wbase = 0, wstep = 1;
  if (tid < 6) { wbase = tid << 4; wstep = 1; }
  else if (tid > 249) { wbase = ((255 - tid) << 4) + 12; wstep = -1; }

  float esum = 0.f;
  for (int r = 0; r < 64; ++r) {
    const int y = y0 + r;
    // issue next input row load early (hides HBM latency under compute+barrier)
    const int yn = y + 7;
    float nxt = 0.f;
    if (yn < 256) nxt = xg[yn * 256 + tid];

    // vertical composed conv (register window); boundary rows via wl
    float vout = 0.f;
    if (y >= 6 && y <= 249) {
      #pragma unroll
      for (int t = 0; t < 13; ++t) vout += wc.c[t] * win[t];
    } else if (y < 6) {
      #pragma unroll
      for (int t = 0; t < 13; ++t) vout += wl[(y << 4) + t] * win[t];
    } else {  // y > 249
      #pragma unroll
      for (int t = 0; t < 13; ++t) vout += wl[((255 - y) << 4) + 12 - t] * win[t];
    }

    const int p = r & 1;
    rb[p][6 + tid] = vout;
    __syncthreads();

    // horizontal composed conv from LDS row (stride-1 b32: conflict-free)
    float h = 0.f;
    #pragma unroll
    for (int t = 0; t < 13; ++t) h += wc.c[t] * rb[p][tid + t];
    if (hfix) {  // exec-masked recompute for 12 edge lanes (wl rows zero OOB taps)
      h = 0.f;
      #pragma unroll
      for (int t = 0; t < 13; ++t) h += wl[wbase + wstep * t] * rb[p][tid + t];
    }

    const float c = win[6] - h;      // win[6] = x(y, tid)
    cg[y * 256 + tid] = c;
    esum += __expf(c);

    #pragma unroll
    for (int i = 0; i < 12; ++i) win[i] = win[i + 1];
    win[12] = nxt;
  }

  #pragma unroll
  for (int off = 32; off >= 1; off >>= 1) esum += __shfl_down(esum, off);
  if ((tid & 63) == 0) atomicAdd(&S[img], esum);
}

// att accumulation: block = (chunk ci of 1024 n's, batch b).
__global__ __launch_bounds__(256) void att_k(const float* __restrict__ ctx,
                                             float* __restrict__ attacc) {
  __shared__ __align__(16) float ct[64 * 68];
  __shared__ __align__(16) float et[64 * 68];
  const int t = threadIdx.x;
  const int ci = blockIdx.x;
  const int b = blockIdx.y;
  const int d0 = (t >> 4) << 2;
  const int e0 = (t & 15) << 2;
  const float* cb = ctx + ((size_t)b << 22);
  float acc[4][4] = {};
  for (int sub = 0; sub < 16; ++sub) {
    const int n0 = (ci << 10) + (sub << 6);
    #pragma unroll
    for (int i = 0; i < 16; ++i) {
      int e = i * 256 + t;
      int d = e >> 6, nl = e & 63;
      float v = cb[((size_t)d << 16) + n0 + nl];
      ct[nl * 68 + d] = v;
      et[nl * 68 + d] = __expf(v);
    }
    __syncthreads();
    #pragma unroll 16
    for (int nl = 0; nl < 64; ++nl) {
      float4 ed = *(const float4*)&et[nl * 68 + d0];
      float4 cv = *(const float4*)&ct[nl * 68 + e0];
      acc[0][0] += ed.x * cv.x; acc[0][1] += ed.x * cv.y; acc[0][2] += ed.x * cv.z; acc[0][3] += ed.x * cv.w;
      acc[1][0] += ed.y * cv.x; acc[1][1] += ed.y * cv.y; acc[1][2] += ed.y * cv.z; acc[1][3] += ed.y * cv.w;
      acc[2][0] += ed.z * cv.x; acc[2][1] += ed.z * cv.y; acc[2][2] += ed.z * cv.z; acc[2][3] += ed.z * cv.w;
      acc[3][0] += ed.w * cv.x; acc[3][1] += ed.w * cv.y; acc[3][2] += ed.w * cv.z; acc[3][3] += ed.w * cv.w;
    }
    __syncthreads();
  }
  float* ap = attacc + ((size_t)(b * 64 + d0) << 6) + e0;
  #pragma unroll
  for (int i = 0; i < 4; ++i) {
    #pragma unroll
    for (int j = 0; j < 4; ++j) atomicAdd(ap + ((size_t)i << 6) + j, acc[i][j]);
  }
}

__global__ __launch_bounds__(256) void fin_k(float* __restrict__ out, const float* __restrict__ S) {
  int i = blockIdx.x * 256 + threadIdx.x;
  out[i] = out[i] / S[i >> 6];
}

extern "C" void kernel_launch(void* const* d_in, const int* in_sizes, int n_in,
                              void* d_out, int out_size, void* d_ws, size_t ws_size,
                              hipStream_t stream) {
  const float* x = (const float*)d_in[0];
  float* out = (float*)d_out;
  float* ctx = (float*)d_ws;                                          // 256 MiB fp32
  float* S    = (float*)((char*)d_ws + (size_t)67108864 * 4);         // 4 KB
  float* wtab = (float*)((char*)d_ws + (size_t)67108864 * 4 + 4096);  // 16 KB
  if (ws_size < (size_t)67108864 * 4 + 4096 + 16384) return;

  // per-level 1-D gaussians in double (matches cv2.getGaussianKernel)
  double gg[3][7];
  double sv = pow(2.0, 1.0 / 3.0);
  for (int lv = 0; lv < 3; ++lv) {
    int k = 2 * lv + 3;
    double sig = 1.6 * pow(sv, lv), sum = 0.0;
    for (int i = 0; i < k; ++i) {
      double a = i - (k - 1) / 2.0;
      gg[lv][i] = exp(-a * a / (2.0 * sig * sig));
      sum += gg[lv][i];
    }
    for (int i = 0; i < k; ++i) gg[lv][i] /= sum;
  }

  G157 gw;
  for (int i = 0; i < 3; ++i) gw.g3[i] = (float)gg[0][i];
  for (int i = 0; i < 5; ++i) gw.g5[i] = (float)gg[1][i];
  for (int i = 0; i < 7; ++i) gw.g7[i] = (float)gg[2][i];

  // interior composed 13-tap (full triple convolution), in double
  WC wc;
  {
    double t35[7] = {0};
    for (int i = 0; i < 3; ++i)
      for (int j = 0; j < 5; ++j) t35[i + j] += gg[0][i] * gg[1][j];
    double t357[13] = {0};
    for (int i = 0; i < 7; ++i)
      for (int j = 0; j < 7; ++j) t357[i + j] += t35[i] * gg[2][j];
    for (int t = 0; t < 13; ++t) wc.c[t] = (float)t357[t];
  }

  zero_k<<<dim3(256), dim3(256), 0, stream>>>(out, S, wtab, gw);
  ctx_k<<<dim3(4096), dim3(256), 0, stream>>>(x, ctx, S, wtab, wc);
  att_k<<<dim3(64, 16), dim3(256), 0, stream>>>(ctx, out);
  fin_k<<<dim3(256), dim3(256), 0, stream>>>(out, S);
}

// Round 5
// 244.985 us; speedup vs baseline: 3.6679x; 1.3598x over previous
//
#include <hip/hip_runtime.h>
#include <hip/hip_bf16.h>
#include <math.h>

typedef short bf16x8 __attribute__((ext_vector_type(8)));
typedef float f32x4  __attribute__((ext_vector_type(4)));

struct WC   { float c[13]; };                 // interior composed 13-tap
struct G157 { float g3[3], g5[5], g7[7]; };   // per-level 1-D gaussians

__device__ __forceinline__ unsigned short f2bf(float f) {
  __hip_bfloat16 h = __float2bfloat16(f);     // RNE
  return *reinterpret_cast<unsigned short*>(&h);
}

// zero out + S; block 0 builds per-position composed weight table wtab[256][16]
__global__ __launch_bounds__(256) void zero_k(float* __restrict__ out, float* __restrict__ S,
                                              float* __restrict__ wtab, G157 gw) {
  int i = blockIdx.x * 256 + threadIdx.x;
  if (i < 65536) out[i] = 0.f;
  if (i < 1024) S[i] = 0.f;
  if (blockIdx.x == 0) {
    int g = threadIdx.x;
    float row[13];
    #pragma unroll
    for (int t = 0; t < 13; ++t) row[t] = 0.f;
    #pragma unroll
    for (int di = -3; di <= 3; ++di) {
      int ii = g + di;
      if ((unsigned)ii >= 256u) continue;
      float w7 = gw.g7[di + 3];
      #pragma unroll
      for (int dj = -2; dj <= 2; ++dj) {
        int jj = ii + dj;
        if ((unsigned)jj >= 256u) continue;
        float c2 = w7 * gw.g5[dj + 2];
        #pragma unroll
        for (int dk = -1; dk <= 1; ++dk) {
          int mm = jj + dk;
          if ((unsigned)mm >= 256u) continue;
          row[di + dj + dk + 6] += c2 * gw.g3[dk + 1];
        }
      }
    }
    #pragma unroll
    for (int t = 0; t < 13; ++t) wtab[(g << 4) + t] = row[t];
    wtab[(g << 4) + 13] = 0.f; wtab[(g << 4) + 14] = 0.f; wtab[(g << 4) + 15] = 0.f;
  }
}

// Register-rolling blur; 2 rows per barrier; bf16 ctx output.
__global__ __launch_bounds__(256) void ctx_k(const float* __restrict__ x,
                                             unsigned short* __restrict__ ctxb,
                                             float* __restrict__ S,
                                             const float* __restrict__ wtab,
                                             WC wc) {
  __shared__ float rb[2][2][268];  // [phase][row-in-pair][6 pad | 256 | 6 pad]
  __shared__ float wl[96];         // boundary weight rows 0..5 (x16)

  const int tid = threadIdx.x;
  const int bi = blockIdx.x;
  const int img = bi >> 2;         // 1024 images
  const int band = bi & 3;         // 4 bands of 64 rows
  const int y0 = band << 6;
  const float* xg = x + ((size_t)img << 16);
  unsigned short* cgb = ctxb + ((size_t)img << 16);

  if (tid < 96) wl[tid] = wtab[tid];
  if (tid < 6) { rb[0][0][tid] = 0.f; rb[0][1][tid] = 0.f; rb[1][0][tid] = 0.f; rb[1][1][tid] = 0.f; }
  if (tid >= 250) { rb[0][0][tid + 12] = 0.f; rb[0][1][tid + 12] = 0.f;
                    rb[1][0][tid + 12] = 0.f; rb[1][1][tid + 12] = 0.f; }

  // 14-row input window: rows y0-6 .. y0+7
  float win[14];
  #pragma unroll
  for (int i = 0; i < 14; ++i) {
    int yy = y0 - 6 + i;
    win[i] = ((unsigned)yy < 256u) ? xg[yy * 256 + tid] : 0.f;
  }
  __syncthreads();

  const bool hfix = (tid < 6) || (tid > 249);
  int wbase = 0, wstep = 1;
  if (tid < 6) { wbase = tid << 4; wstep = 1; }
  else if (tid > 249) { wbase = ((255 - tid) << 4) + 12; wstep = -1; }

  float esum = 0.f;
  for (int r = 0; r < 64; r += 2) {
    const int y = y0 + r;
    float nxt0 = 0.f, nxt1 = 0.f;
    if (y + 8 < 256) nxt0 = xg[(y + 8) * 256 + tid];
    if (y + 9 < 256) nxt1 = xg[(y + 9) * 256 + tid];

    // vertical composed conv for rows y (win[0..12]) and y+1 (win[1..13])
    float v0 = 0.f, v1 = 0.f;
    if (y >= 6 && y + 1 <= 249) {
      #pragma unroll
      for (int t = 0; t < 13; ++t) { v0 += wc.c[t] * win[t]; v1 += wc.c[t] * win[t + 1]; }
    } else {
      // boundary rows (wave-uniform): handle each row by its own regime
      if (y < 6) {
        #pragma unroll
        for (int t = 0; t < 13; ++t) v0 += wl[(y << 4) + t] * win[t];
      } else if (y > 249) {
        #pragma unroll
        for (int t = 0; t < 13; ++t) v0 += wl[((255 - y) << 4) + 12 - t] * win[t];
      } else {
        #pragma unroll
        for (int t = 0; t < 13; ++t) v0 += wc.c[t] * win[t];
      }
      int y1 = y + 1;
      if (y1 < 6) {
        #pragma unroll
        for (int t = 0; t < 13; ++t) v1 += wl[(y1 << 4) + t] * win[t + 1];
      } else if (y1 > 249) {
        #pragma unroll
        for (int t = 0; t < 13; ++t) v1 += wl[((255 - y1) << 4) + 12 - t] * win[t + 1];
      } else {
        #pragma unroll
        for (int t = 0; t < 13; ++t) v1 += wc.c[t] * win[t + 1];
      }
    }

    const int p = (r >> 1) & 1;
    rb[p][0][6 + tid] = v0;
    rb[p][1][6 + tid] = v1;
    __syncthreads();

    float h0 = 0.f, h1 = 0.f;
    if (!hfix) {
      #pragma unroll
      for (int t = 0; t < 13; ++t) {
        float w = wc.c[t];
        h0 += w * rb[p][0][tid + t];
        h1 += w * rb[p][1][tid + t];
      }
    } else {
      #pragma unroll
      for (int t = 0; t < 13; ++t) {
        float w = wl[wbase + wstep * t];
        h0 += w * rb[p][0][tid + t];
        h1 += w * rb[p][1][tid + t];
      }
    }

    unsigned short s0 = f2bf(win[6] - h0);
    unsigned short s1 = f2bf(win[7] - h1);
    cgb[y * 256 + tid] = s0;
    cgb[(y + 1) * 256 + tid] = s1;
    // esum from the ROUNDED value: numerator/denominator stay consistent
    esum += __expf(__uint_as_float((unsigned)s0 << 16)) +
            __expf(__uint_as_float((unsigned)s1 << 16));

    #pragma unroll
    for (int i = 0; i < 12; ++i) win[i] = win[i + 2];
    win[12] = nxt0; win[13] = nxt1;
  }

  #pragma unroll
  for (int off = 32; off >= 1; off >>= 1) esum += __shfl_down(esum, off);
  if ((tid & 63) == 0) atomicAdd(&S[img], esum);
}

// MFMA att: per batch b, att = P * C^T, P = exp(C), C = ctx[b] (64 x 65536 bf16).
// Block = 4 waves; wave wv owns rows 16wv..16wv+15, loops 4 col-blocks.
// A and B fragments are contiguous bf16x8 loads from row-major [64][65536].
__global__ __launch_bounds__(256) void att_k(const unsigned short* __restrict__ ctxb,
                                             float* __restrict__ attacc) {
  const int t = threadIdx.x;
  const int wv = t >> 6, lane = t & 63;
  const int rw = lane & 15;        // A-row / B-col within 16
  const int kq = lane >> 4;        // k-subgroup (8 elems each)
  const int ci = blockIdx.x;       // 32 chunks of 2048
  const int b = blockIdx.y;        // 16 batches
  const unsigned short* cb = ctxb + ((size_t)b << 22);
  const int n0 = (ci << 11) + (kq << 3);

  const unsigned short* pA  = cb + (((size_t)(16 * wv + rw)) << 16) + n0;
  const unsigned short* pB  = cb + (((size_t)rw) << 16) + n0;  // col-block k adds k*16<<16

  f32x4 acc0 = {0.f, 0.f, 0.f, 0.f}, acc1 = acc0, acc2 = acc0, acc3 = acc0;

  #pragma unroll 8
  for (int ks = 0; ks < 2048; ks += 32) {
    bf16x8 av = *(const bf16x8*)(pA + ks);
    bf16x8 ev;
    const unsigned* au = (const unsigned*)&av;
    unsigned* eu = (unsigned*)&ev;
    #pragma unroll
    for (int j = 0; j < 4; ++j) {
      unsigned w = au[j];
      float lo = __uint_as_float(w << 16);
      float hi = __uint_as_float(w & 0xffff0000u);
      eu[j] = ((unsigned)f2bf(__expf(hi)) << 16) | (unsigned)f2bf(__expf(lo));
    }
    bf16x8 b0 = *(const bf16x8*)(pB + ks);
    bf16x8 b1 = *(const bf16x8*)(pB + (size_t)(16 << 16) + ks);
    bf16x8 b2 = *(const bf16x8*)(pB + (size_t)(32 << 16) + ks);
    bf16x8 b3 = *(const bf16x8*)(pB + (size_t)(48 << 16) + ks);
    acc0 = __builtin_amdgcn_mfma_f32_16x16x32_bf16(ev, b0, acc0, 0, 0, 0);
    acc1 = __builtin_amdgcn_mfma_f32_16x16x32_bf16(ev, b1, acc1, 0, 0, 0);
    acc2 = __builtin_amdgcn_mfma_f32_16x16x32_bf16(ev, b2, acc2, 0, 0, 0);
    acc3 = __builtin_amdgcn_mfma_f32_16x16x32_bf16(ev, b3, acc3, 0, 0, 0);
  }

  // C/D layout: col = lane&15 (e_local), row = (lane>>4)*4 + reg (d_local)
  const int dl = kq << 2;
  float* ap = attacc + (((size_t)((b << 6) + (wv << 4) + dl)) << 6) + rw;
  #pragma unroll
  for (int reg = 0; reg < 4; ++reg) {
    atomicAdd(ap + ((size_t)reg << 6) + 0,  acc0[reg]);
    atomicAdd(ap + ((size_t)reg << 6) + 16, acc1[reg]);
    atomicAdd(ap + ((size_t)reg << 6) + 32, acc2[reg]);
    atomicAdd(ap + ((size_t)reg << 6) + 48, acc3[reg]);
  }
}

__global__ __launch_bounds__(256) void fin_k(float* __restrict__ out, const float* __restrict__ S) {
  int i = blockIdx.x * 256 + threadIdx.x;
  out[i] = out[i] / S[i >> 6];
}

extern "C" void kernel_launch(void* const* d_in, const int* in_sizes, int n_in,
                              void* d_out, int out_size, void* d_ws, size_t ws_size,
                              hipStream_t stream) {
  const float* x = (const float*)d_in[0];
  float* out = (float*)d_out;
  unsigned short* ctxb = (unsigned short*)d_ws;                        // 134 MiB bf16
  float* S    = (float*)((char*)d_ws + (size_t)67108864 * 2);          // 4 KB
  float* wtab = (float*)((char*)d_ws + (size_t)67108864 * 2 + 4096);   // 16 KB
  if (ws_size < (size_t)67108864 * 2 + 4096 + 16384) return;

  // per-level 1-D gaussians in double (matches cv2.getGaussianKernel)
  double gg[3][7];
  double sv = pow(2.0, 1.0 / 3.0);
  for (int lv = 0; lv < 3; ++lv) {
    int k = 2 * lv + 3;
    double sig = 1.6 * pow(sv, lv), sum = 0.0;
    for (int i = 0; i < k; ++i) {
      double a = i - (k - 1) / 2.0;
      gg[lv][i] = exp(-a * a / (2.0 * sig * sig));
      sum += gg[lv][i];
    }
    for (int i = 0; i < k; ++i) gg[lv][i] /= sum;
  }

  G157 gw;
  for (int i = 0; i < 3; ++i) gw.g3[i] = (float)gg[0][i];
  for (int i = 0; i < 5; ++i) gw.g5[i] = (float)gg[1][i];
  for (int i = 0; i < 7; ++i) gw.g7[i] = (float)gg[2][i];

  WC wc;
  {
    double t35[7] = {0};
    for (int i = 0; i < 3; ++i)
      for (int j = 0; j < 5; ++j) t35[i + j] += gg[0][i] * gg[1][j];
    double t357[13] = {0};
    for (int i = 0; i < 7; ++i)
      for (int j = 0; j < 7; ++j) t357[i + j] += t35[i] * gg[2][j];
    for (int t = 0; t < 13; ++t) wc.c[t] = (float)t357[t];
  }

  zero_k<<<dim3(256), dim3(256), 0, stream>>>(out, S, wtab, gw);
  ctx_k<<<dim3(4096), dim3(256), 0, stream>>>(x, ctxb, S, wtab, wc);
  att_k<<<dim3(32, 16), dim3(256), 0, stream>>>(ctxb, out);
  fin_k<<<dim3(256), dim3(256), 0, stream>>>(out, S);
}

// Round 6
// 220.096 us; speedup vs baseline: 4.0827x; 1.1131x over previous
//
#include <hip/hip_runtime.h>
#include <hip/hip_bf16.h>
#include <math.h>

typedef short bf16x8 __attribute__((ext_vector_type(8)));
typedef float f32x4  __attribute__((ext_vector_type(4)));

struct WC   { float c[13]; };                 // interior composed 13-tap
struct G157 { float g3[3], g5[5], g7[7]; };   // per-level 1-D gaussians

__device__ __forceinline__ unsigned short f2bf(float f) {
  __hip_bfloat16 h = __float2bfloat16(f);     // RNE
  return *reinterpret_cast<unsigned short*>(&h);
}
__device__ __forceinline__ float bf2f(unsigned short s) {
  return __uint_as_float((unsigned)s << 16);
}

// zero out + S; block 0 builds per-position composed weight table wtab[256][16]
__global__ __launch_bounds__(256) void zero_k(float* __restrict__ out, float* __restrict__ S,
                                              float* __restrict__ wtab, G157 gw) {
  int i = blockIdx.x * 256 + threadIdx.x;
  if (i < 65536) out[i] = 0.f;
  if (i < 1024) S[i] = 0.f;
  if (blockIdx.x == 0) {
    int g = threadIdx.x;
    float row[13];
    #pragma unroll
    for (int t = 0; t < 13; ++t) row[t] = 0.f;
    #pragma unroll
    for (int di = -3; di <= 3; ++di) {
      int ii = g + di;
      if ((unsigned)ii >= 256u) continue;
      float w7 = gw.g7[di + 3];
      #pragma unroll
      for (int dj = -2; dj <= 2; ++dj) {
        int jj = ii + dj;
        if ((unsigned)jj >= 256u) continue;
        float c2 = w7 * gw.g5[dj + 2];
        #pragma unroll
        for (int dk = -1; dk <= 1; ++dk) {
          int mm = jj + dk;
          if ((unsigned)mm >= 256u) continue;
          row[di + dj + dk + 6] += c2 * gw.g3[dk + 1];
        }
      }
    }
    #pragma unroll
    for (int t = 0; t < 13; ++t) wtab[(g << 4) + t] = row[t];
    wtab[(g << 4) + 13] = 0.f; wtab[(g << 4) + 14] = 0.f; wtab[(g << 4) + 15] = 0.f;
  }
}

// ctx = x - blur(x), bf16 out. v-conv per-column register window (fully unrolled ring),
// h-conv in 4-cols/lane layout with aligned ds_read_b128. Edge cols (0..5,250..255)
// fixed exactly in an in-block post-pass from saved v-results.
__global__ __launch_bounds__(256) void ctx_k(const float* __restrict__ x,
                                             unsigned short* __restrict__ ctxb,
                                             float* __restrict__ S,
                                             const float* __restrict__ wtab,
                                             WC wc) {
  __shared__ __align__(16) float rb[2][4][272];   // v-results: 8 pad | 256 | 8 pad
  __shared__ __align__(16) float xrb[2][4][256];  // x rows (for ctx = x - h)
  __shared__ float vs[64][24];                    // v-results at cols 0..11 / 244..255
  __shared__ float wl[96];                        // boundary rows 0..5 (x16)

  const int tid = threadIdx.x;
  const int img = blockIdx.x >> 2;
  const int band = blockIdx.x & 3;
  const int y0 = band << 6;
  const float* xg = x + ((size_t)img << 16);
  unsigned short* cgb = ctxb + ((size_t)img << 16);

  if (tid < 96) wl[tid] = wtab[tid];
  if (tid < 128) {  // zero rb pads once
    int bb = (tid >> 6) & 1, rr = (tid >> 4) & 3, pp = tid & 15;
    rb[bb][rr][(pp < 8) ? pp : (256 + pp)] = 0.f;
  }

  // input ring: slot(row) = (row - y0 + 6) mod 24. Init rows y0-6 .. y0+13.
  float win[24];
  #pragma unroll
  for (int i = 0; i < 24; ++i) win[i] = 0.f;
  #pragma unroll
  for (int i = 0; i < 20; ++i) {
    int yy = y0 - 6 + i;
    if ((unsigned)yy < 256u) win[i] = xg[yy * 256 + tid];
  }
  __syncthreads();

  const bool vsave = (tid < 12) || (tid >= 244);
  const int vsidx = (tid < 12) ? tid : (tid - 232);
  const int g = tid >> 6, q = tid & 63;   // h-phase: wave g -> row, lane q -> cols 4q..4q+3

  float esum = 0.f;

  #pragma unroll
  for (int it = 0; it < 16; ++it) {
    const int y = y0 + 4 * it;
    // prefetch rows y+14..y+17 (2-iteration lookahead); band needs rows up to y0+69
    #pragma unroll
    for (int j = 0; j < 4; ++j) {
      if (4 * it + 14 + j < 70) {
        int yy = y + 14 + j;
        float v = 0.f;
        if (yy < 256) v = xg[yy * 256 + tid];
        win[(4 * it + 20 + j) % 24] = v;
      }
    }
    // vertical conv, 4 rows, per-column (compile-time ring indices)
    float vv[4];
    if (it > 1 && it < 14) {  // rows y0+8..y0+55: always interior
      #pragma unroll
      for (int r = 0; r < 4; ++r) {
        float a = 0.f;
        #pragma unroll
        for (int t = 0; t < 13; ++t) a += wc.c[t] * win[(4 * it + r + t) % 24];
        vv[r] = a;
      }
    } else {
      #pragma unroll
      for (int r = 0; r < 4; ++r) {
        int yr = y + r;
        float a = 0.f;
        if (yr < 6) {
          #pragma unroll
          for (int t = 0; t < 13; ++t) a += wl[(yr << 4) + t] * win[(4 * it + r + t) % 24];
        } else if (yr > 249) {
          #pragma unroll
          for (int t = 0; t < 13; ++t) a += wl[((255 - yr) << 4) + (12 - t)] * win[(4 * it + r + t) % 24];
        } else {
          #pragma unroll
          for (int t = 0; t < 13; ++t) a += wc.c[t] * win[(4 * it + r + t) % 24];
        }
        vv[r] = a;
      }
    }
    const int buf = it & 1;
    #pragma unroll
    for (int r = 0; r < 4; ++r) {
      rb[buf][r][8 + tid] = vv[r];
      xrb[buf][r][tid] = win[(4 * it + 6 + r) % 24];
    }
    if (vsave) {
      #pragma unroll
      for (int r = 0; r < 4; ++r) vs[4 * it + r][vsidx] = vv[r];
    }
    __syncthreads();

    // horizontal conv: aligned b128 reads; cols 4q+j use f[2+j .. 14+j]
    const float* hp = &rb[buf][g][4 * q];
    float f[20];
    *(float4*)&f[0]  = *(const float4*)(hp + 0);
    *(float4*)&f[4]  = *(const float4*)(hp + 4);
    *(float4*)&f[8]  = *(const float4*)(hp + 8);
    *(float4*)&f[12] = *(const float4*)(hp + 12);
    *(float4*)&f[16] = *(const float4*)(hp + 16);
    float4 xq = *(const float4*)&xrb[buf][g][4 * q];
    float h0 = 0.f, h1 = 0.f, h2 = 0.f, h3 = 0.f;
    #pragma unroll
    for (int t = 0; t < 13; ++t) {
      float w = wc.c[t];
      h0 += w * f[2 + t]; h1 += w * f[3 + t]; h2 += w * f[4 + t]; h3 += w * f[5 + t];
    }
    unsigned short s0 = f2bf(xq.x - h0), s1 = f2bf(xq.y - h1);
    unsigned short s2 = f2bf(xq.z - h2), s3 = f2bf(xq.w - h3);
    *(ushort4*)(cgb + (size_t)(y + g) * 256 + 4 * q) = make_ushort4(s0, s1, s2, s3);
    const int cb0 = 4 * q;
    // interior cols only; edge cols (0..5,250..255) contribute in the post-pass
    esum += ((cb0 + 0 >= 6) && (cb0 + 0 <= 249)) ? __expf(bf2f(s0)) : 0.f;
    esum += ((cb0 + 1 >= 6) && (cb0 + 1 <= 249)) ? __expf(bf2f(s1)) : 0.f;
    esum += ((cb0 + 2 >= 6) && (cb0 + 2 <= 249)) ? __expf(bf2f(s2)) : 0.f;
    esum += ((cb0 + 3 >= 6) && (cb0 + 3 <= 249)) ? __expf(bf2f(s3)) : 0.f;
  }

  __syncthreads();
  // post-pass: exact h-conv for 12 edge cols x 64 rows from saved v-results
  #pragma unroll
  for (int k = 0; k < 3; ++k) {
    int e = k * 256 + tid;           // 768 elements
    int row = e / 12;
    int ce = e - row * 12;
    int col = (ce < 6) ? ce : (244 + ce);   // {0..5, 250..255}
    float h = 0.f;
    if (ce < 6) {
      #pragma unroll
      for (int t = 0; t < 13; ++t) {
        int vc = col - 6 + t;
        if (vc >= 0) h += wl[(col << 4) + t] * vs[row][vc];
      }
    } else {
      #pragma unroll
      for (int t = 0; t < 13; ++t) {
        int vc = col - 6 + t;
        if (vc < 256) h += wl[((255 - col) << 4) + (12 - t)] * vs[row][vc - 232];
      }
    }
    int yrow = y0 + row;
    float xval = xg[yrow * 256 + col];
    unsigned short sn = f2bf(xval - h);
    cgb[yrow * 256 + col] = sn;
    esum += __expf(bf2f(sn));
  }

  #pragma unroll
  for (int off = 32; off >= 1; off >>= 1) esum += __shfl_down(esum, off);
  if ((tid & 63) == 0) atomicAdd(&S[img], esum);
}

// MFMA att: per batch b, att = P * C^T, P = exp(C), C = ctx[b] (64 x 65536 bf16).
__global__ __launch_bounds__(256) void att_k(const unsigned short* __restrict__ ctxb,
                                             float* __restrict__ attacc) {
  const int t = threadIdx.x;
  const int wv = t >> 6, lane = t & 63;
  const int rw = lane & 15;        // A-row / B-col within 16
  const int kq = lane >> 4;        // k-subgroup (8 elems each)
  const int ci = blockIdx.x;       // 64 chunks of 1024
  const int b = blockIdx.y;        // 16 batches
  const unsigned short* cb = ctxb + ((size_t)b << 22);
  const int n0 = (ci << 10) + (kq << 3);

  const unsigned short* pA = cb + (((size_t)(16 * wv + rw)) << 16) + n0;
  const unsigned short* pB = cb + (((size_t)rw) << 16) + n0;

  f32x4 acc0 = {0.f, 0.f, 0.f, 0.f}, acc1 = acc0, acc2 = acc0, acc3 = acc0;

  #pragma unroll 8
  for (int ks = 0; ks < 1024; ks += 32) {
    bf16x8 av = *(const bf16x8*)(pA + ks);
    bf16x8 ev;
    const unsigned* au = (const unsigned*)&av;
    unsigned* eu = (unsigned*)&ev;
    #pragma unroll
    for (int j = 0; j < 4; ++j) {
      unsigned w = au[j];
      float lo = __uint_as_float(w << 16);
      float hi = __uint_as_float(w & 0xffff0000u);
      eu[j] = ((unsigned)f2bf(__expf(hi)) << 16) | (unsigned)f2bf(__expf(lo));
    }
    bf16x8 b0 = *(const bf16x8*)(pB + ks);
    bf16x8 b1 = *(const bf16x8*)(pB + (size_t)(16 << 16) + ks);
    bf16x8 b2 = *(const bf16x8*)(pB + (size_t)(32 << 16) + ks);
    bf16x8 b3 = *(const bf16x8*)(pB + (size_t)(48 << 16) + ks);
    acc0 = __builtin_amdgcn_mfma_f32_16x16x32_bf16(ev, b0, acc0, 0, 0, 0);
    acc1 = __builtin_amdgcn_mfma_f32_16x16x32_bf16(ev, b1, acc1, 0, 0, 0);
    acc2 = __builtin_amdgcn_mfma_f32_16x16x32_bf16(ev, b2, acc2, 0, 0, 0);
    acc3 = __builtin_amdgcn_mfma_f32_16x16x32_bf16(ev, b3, acc3, 0, 0, 0);
  }

  // C/D layout: col = lane&15, row = (lane>>4)*4 + reg
  const int dl = kq << 2;
  float* ap = attacc + (((size_t)((b << 6) + (wv << 4) + dl)) << 6) + rw;
  #pragma unroll
  for (int reg = 0; reg < 4; ++reg) {
    atomicAdd(ap + ((size_t)reg << 6) + 0,  acc0[reg]);
    atomicAdd(ap + ((size_t)reg << 6) + 16, acc1[reg]);
    atomicAdd(ap + ((size_t)reg << 6) + 32, acc2[reg]);
    atomicAdd(ap + ((size_t)reg << 6) + 48, acc3[reg]);
  }
}

__global__ __launch_bounds__(256) void fin_k(float* __restrict__ out, const float* __restrict__ S) {
  int i = blockIdx.x * 256 + threadIdx.x;
  out[i] = out[i] / S[i >> 6];
}

extern "C" void kernel_launch(void* const* d_in, const int* in_sizes, int n_in,
                              void* d_out, int out_size, void* d_ws, size_t ws_size,
                              hipStream_t stream) {
  const float* x = (const float*)d_in[0];
  float* out = (float*)d_out;
  unsigned short* ctxb = (unsigned short*)d_ws;                        // 134 MiB bf16
  float* S    = (float*)((char*)d_ws + (size_t)67108864 * 2);          // 4 KB
  float* wtab = (float*)((char*)d_ws + (size_t)67108864 * 2 + 4096);   // 16 KB
  if (ws_size < (size_t)67108864 * 2 + 4096 + 16384) return;

  // per-level 1-D gaussians in double (matches cv2.getGaussianKernel)
  double gg[3][7];
  double sv = pow(2.0, 1.0 / 3.0);
  for (int lv = 0; lv < 3; ++lv) {
    int k = 2 * lv + 3;
    double sig = 1.6 * pow(sv, lv), sum = 0.0;
    for (int i = 0; i < k; ++i) {
      double a = i - (k - 1) / 2.0;
      gg[lv][i] = exp(-a * a / (2.0 * sig * sig));
      sum += gg[lv][i];
    }
    for (int i = 0; i < k; ++i) gg[lv][i] /= sum;
  }

  G157 gw;
  for (int i = 0; i < 3; ++i) gw.g3[i] = (float)gg[0][i];
  for (int i = 0; i < 5; ++i) gw.g5[i] = (float)gg[1][i];
  for (int i = 0; i < 7; ++i) gw.g7[i] = (float)gg[2][i];

  WC wc;
  {
    double t35[7] = {0};
    for (int i = 0; i < 3; ++i)
      for (int j = 0; j < 5; ++j) t35[i + j] += gg[0][i] * gg[1][j];
    double t357[13] = {0};
    for (int i = 0; i < 7; ++i)
      for (int j = 0; j < 7; ++j) t357[i + j] += t35[i] * gg[2][j];
    for (int t = 0; t < 13; ++t) wc.c[t] = (float)t357[t];
  }

  zero_k<<<dim3(256), dim3(256), 0, stream>>>(out, S, wtab, gw);
  ctx_k<<<dim3(4096), dim3(256), 0, stream>>>(x, ctxb, S, wtab, wc);
  att_k<<<dim3(64, 16), dim3(256), 0, stream>>>(ctxb, out);
  fin_k<<<dim3(256), dim3(256), 0, stream>>>(out, S);
}